// Round 2
// baseline (606.636 us; speedup 1.0000x reference)
//
#include <hip/hip_runtime.h>

typedef unsigned short u16;
typedef unsigned int   u32;

#define EPSF 1e-5f

typedef __attribute__((ext_vector_type(8))) short bf16x8;
typedef __attribute__((ext_vector_type(4))) float f32x4;

__device__ __forceinline__ u16 f2us(float f){
  union { float f; u32 i; } v; v.f = f;
  u32 i = v.i;
  return (u16)((i + 0x7FFFu + ((i >> 16) & 1u)) >> 16);   // RNE f32->bf16
}
__device__ __forceinline__ float us2f(u16 u){
  union { u32 i; float f; } v; v.i = ((u32)u) << 16; return v.f;
}
__device__ __forceinline__ float hswish(float x){
  return x * fminf(fmaxf(x + 3.f, 0.f), 6.f) * (1.f/6.f);
}
__device__ __forceinline__ float sigm(float x){ return 1.f / (1.f + expf(-x)); }

// ---- workspace layout (fp32 elements) ----
#define WS_PARTIAL 0          // 512*3200 = 1638400 (reuses XV/XT/XS space, dead after k3)
#define WS_XV      0          // 1228800
#define WS_XT      1228800    // 102400
#define WS_XS      1331200    // 1331200
#define WS_S       2662400    // 20800
#define WS_GATE    2683200    // 1600
#define WS_PART1   2684800    // 256
#define WS_ACCXS   2685056    // 128
#define WS_COLSTAT 2685184    // 3200
#define WS_ABN     2688384    // 1600
#define WS_BBN     2689984    // 1600

__global__ __launch_bounds__(256) void k_zero(float* p, int cnt){
  int i = blockIdx.x*256 + threadIdx.x;
  if (i < cnt) p[i] = 0.f;
}

// K1: per (n,c) slab: xv_pre[n,c,t], xt_pre[n,c,v], global BN stat partials.
__global__ __launch_bounds__(256) void k1(const float* __restrict__ x0,
    const float* __restrict__ Wv, const float* __restrict__ bv,
    const float* __restrict__ Wt, const float* __restrict__ bt,
    float* __restrict__ ws)
{
  __shared__ float slab[7500];
  __shared__ float wvc[25];
  __shared__ float wts[300];
  __shared__ float colS[25];
  __shared__ float red[8];
  int blk = blockIdx.x;           // n*64 + c
  int c = blk & 63;
  int tid = threadIdx.x;
  const float4* src = (const float4*)(x0) + blk*1875;
  float4* dst = (float4*)slab;
  for (int i = tid; i < 1875; i += 256) dst[i] = src[i];
  int cm = c % 25;
  if (tid < 25){ wvc[tid] = Wv[(tid - cm + 25) % 25]; colS[tid] = 0.f; }
  for (int i = tid; i < 300; i += 256) wts[i] = Wt[i];
  __syncthreads();
  float bvf = bv[0];
  float s1 = 0.f, s2 = 0.f;
  float ca[25];
  #pragma unroll
  for (int u = 0; u < 25; u++) ca[u] = 0.f;
  for (int t = tid; t < 300; t += 256){
    const float* row = &slab[t*25];
    float wt = wts[t];
    float xv = bvf;
    #pragma unroll
    for (int u = 0; u < 25; u++){
      float xf = row[u];
      xv += wvc[u] * xf;
      ca[u] += wt * xf;
    }
    ws[WS_XV + blk*300 + t] = xv;
    s1 += xv; s2 += xv*xv;
  }
  #pragma unroll
  for (int off = 32; off >= 1; off >>= 1){
    s1 += __shfl_xor(s1, off);
    s2 += __shfl_xor(s2, off);
    #pragma unroll
    for (int u = 0; u < 25; u++) ca[u] += __shfl_xor(ca[u], off);
  }
  int lane = tid & 63, wvi = tid >> 6;
  if (lane == 0){
    #pragma unroll
    for (int u = 0; u < 25; u++) atomicAdd(&colS[u], ca[u]);
    red[wvi] = s1; red[4 + wvi] = s2;
  }
  __syncthreads();
  if (wvi == 0){
    float btf = bt[0];
    float val = 0.f;
    if (lane < 25){
      val = colS[(lane + cm) % 25] + btf;
      ws[WS_XT + blk*25 + lane] = val;
    }
    float t1 = val, t2 = val*val;
    #pragma unroll
    for (int off = 32; off >= 1; off >>= 1){ t1 += __shfl_xor(t1, off); t2 += __shfl_xor(t2, off); }
    if (lane == 0){
      float* slot = &ws[WS_PART1 + (blk & 63)*4];
      atomicAdd(slot+0, red[0]+red[1]+red[2]+red[3]);
      atomicAdd(slot+1, red[4]+red[5]+red[6]+red[7]);
      atomicAdd(slot+2, t1);
      atomicAdd(slot+3, t2);
    }
  }
}

// K2: xs_pre[n,o,l] = sum_c Ws[o,c]*xs[n,c,l]; per-o stats.
__global__ __launch_bounds__(256) void k2(
    const float* __restrict__ Ws_, const float* __restrict__ gv, const float* __restrict__ bev,
    const float* __restrict__ gt, const float* __restrict__ bet,
    float* __restrict__ ws)
{
  __shared__ float xsc[64*82];
  __shared__ float wsl[64*65];
  __shared__ float accs[128];
  __shared__ float bnp[4];
  int tid = threadIdx.x;
  int n = blockIdx.x >> 2;
  int chunk = blockIdx.x & 3;
  int l0 = chunk * 82;
  int cw = (325 - l0 < 82) ? (325 - l0) : 82;
  if (tid < 64){
    float p0 = ws[WS_PART1 + tid*4 + 0];
    float p1 = ws[WS_PART1 + tid*4 + 1];
    float p2 = ws[WS_PART1 + tid*4 + 2];
    float p3 = ws[WS_PART1 + tid*4 + 3];
    #pragma unroll
    for (int off = 32; off >= 1; off >>= 1){
      p0 += __shfl_xor(p0, off); p1 += __shfl_xor(p1, off);
      p2 += __shfl_xor(p2, off); p3 += __shfl_xor(p3, off);
    }
    if (tid == 0){
      float Mv = 1228800.f;
      float mv = p0 / Mv;
      float varv = p1 / Mv - mv*mv;
      float av = gv[0] * rsqrtf(varv + EPSF);
      bnp[0] = av; bnp[1] = bev[0] - mv*av;
      float Mt = 102400.f;
      float mt = p2 / Mt;
      float vart = p3 / Mt - mt*mt;
      float at = gt[0] * rsqrtf(vart + EPSF);
      bnp[2] = at; bnp[3] = bet[0] - mt*at;
    }
  }
  for (int i = tid; i < 4096; i += 256){
    int o = i >> 6, cc = i & 63;
    wsl[o*65 + cc] = Ws_[i];
  }
  if (tid < 128) accs[tid] = 0.f;
  __syncthreads();
  float a_v = bnp[0], b_v = bnp[1], a_t = bnp[2], b_t = bnp[3];
  for (int i = tid; i < 64*cw; i += 256){
    int ch = i / cw, li = i - ch*cw;
    int f = ch*325 + l0 + li;
    float e;
    if (f < 1600) e = ws[WS_XT + n*1600 + f] * a_t + b_t;
    else          e = ws[WS_XV + n*19200 + (f - 1600)] * a_v + b_v;
    xsc[ch*82 + li] = hswish(e);
  }
  __syncthreads();
  int o = tid & 63;
  float s1 = 0.f, s2 = 0.f;
  for (int i = tid; i < 64*cw; i += 256){
    int li = i >> 6;
    float acc = 0.f;
    #pragma unroll 8
    for (int cc = 0; cc < 64; cc++)
      acc += wsl[o*65 + cc] * xsc[cc*82 + li];
    ws[WS_XS + (n*64 + o)*325 + l0 + li] = acc;
    s1 += acc; s2 += acc*acc;
  }
  atomicAdd(&accs[o*2+0], s1);
  atomicAdd(&accs[o*2+1], s2);
  __syncthreads();
  if (tid < 128) atomicAdd(&ws[WS_ACCXS + tid], accs[tid]);
}

// K3: S[d,l] = sum_n hardswish(bn_s(xs_pre[n,d,l]))
__global__ __launch_bounds__(256) void k3(const float* __restrict__ gs, const float* __restrict__ bes,
                                          float* __restrict__ ws)
{
  int i = blockIdx.x*256 + threadIdx.x;
  if (i >= 20800) return;
  int dch = i / 325, l = i - dch*325;
  float s1 = ws[WS_ACCXS + dch*2], s2 = ws[WS_ACCXS + dch*2 + 1];
  float m = s1 / 20800.f;
  float var = s2 / 20800.f - m*m;
  float a = gs[dch] * rsqrtf(var + EPSF);
  float b = bes[dch] - m*a;
  float sum = 0.f;
  for (int n = 0; n < 64; n++)
    sum += hswish(ws[WS_XS + (n*64 + dch)*325 + l] * a + b);
  ws[WS_S + i] = sum;
}

// K4: x_time out + gate
__global__ __launch_bounds__(256) void k4(const float* __restrict__ Wt2, const float* __restrict__ bt2,
    const float* __restrict__ Wv2, const float* __restrict__ bv2,
    float* __restrict__ out2, float* __restrict__ ws)
{
  int i = blockIdx.x*256 + threadIdx.x;
  if (i < 19200){
    int o = i / 300, t = i - o*300;
    float acc = 0.f;
    #pragma unroll 8
    for (int dd = 0; dd < 64; dd++)
      acc += Wt2[o*64+dd] * ws[WS_S + dd*325 + t];
    out2[i] = sigm(acc * (1.f/64.f) + bt2[o]);
  } else if (i < 20800){
    int g = i - 19200;
    int v = g >> 6, cc = g & 63;
    float acc = 0.f;
    #pragma unroll 8
    for (int dd = 0; dd < 64; dd++)
      acc += Wv2[cc*64+dd] * ws[WS_S + dd*325 + 300 + v];
    ws[WS_GATE + v*64 + cc] = tanhf(sigm(acc * (1.f/64.f) + bv2[cc])) + 1.f;
  }
}

// K5: GEMM stats pass. Gather indices/gates hoisted into registers (chunk-invariant);
// paired u32 zsh writes. Register sum/sumsq accumulators, LDS flush once,
// non-atomic private partial slice.
__global__ __launch_bounds__(512, 4) void k5(const float* __restrict__ x0,
    const float* __restrict__ Lw, float* __restrict__ ws)
{
  __shared__ u16 xraw[64*154];
  __shared__ u16 zsh[160*72];
  __shared__ u16 lwt[64*72];
  __shared__ float gate[1600];
  __shared__ float colacc[3300];
  int tid = threadIdx.x;
  int n = blockIdx.x >> 3, e8 = blockIdx.x & 7;
  int c0 = (e8*50) >> 3, c1 = ((e8+1)*50) >> 3;   // 6 or 7 chunks of 6 t-steps
  const float2* xsrc = (const float2*)x0;

  for (int i = tid; i < 1600; i += 512) gate[i] = ws[WS_GATE + i];
  for (int i = tid; i < 4096; i += 512){
    int c = i >> 6, d = i & 63;                    // coalesced Lw read
    lwt[d*72 + c] = f2us(Lw[c*64 + d]);
  }
  for (int i = tid; i < 3300; i += 512) colacc[i] = 0.f;
  for (int i = tid; i < 640; i += 512){ int c = i & 63, r = 150 + (i >> 6); zsh[r*72 + c] = 0; }
  // stage first chunk
  for (int i = tid; i < 4800; i += 512){
    int c = i / 75, j = i - c*75;
    float2 xy = xsrc[(n*64 + c)*3750 + c0*75 + j];
    *(u32*)&xraw[c*154 + 2*j] = (u32)f2us(xy.x) | ((u32)f2us(xy.y) << 16);
  }
  __syncthreads();                                  // gate ready for precompute

  // --- chunk-invariant gather slots (pairs of adjacent c) ---
  u32 gsrc[10]; int gdst[10]; float gA[10], gB[10];
  #pragma unroll
  for (int k = 0; k < 10; k++){
    int p = tid + k*512;
    if (k < 9 || p < 4800){
      int cp = (p & 31)*2, r = p >> 5;
      int v = r % 25;
      int base = r - v;
      int u1 = (v + cp) % 25;
      int u2 = (v + cp + 1) % 25;
      gsrc[k] = (u32)(cp*154 + base + u1) | ((u32)((cp+1)*154 + base + u2) << 16);
      gdst[k] = r*72 + cp;
      gA[k] = gate[v*64 + cp];
      gB[k] = gate[v*64 + cp + 1];
    }
  }

  int lane = tid & 63, wvi = tid >> 6;
  int m16 = lane & 15, kq = lane >> 4;
  int dd = (wvi & 3)*16 + m16;
  bf16x8 b0, b1;
  float s_acc[20], q_acc[20];
  #pragma unroll
  for (int z = 0; z < 20; z++){ s_acc[z] = 0.f; q_acc[z] = 0.f; }

  for (int cc = c0; cc < c1; cc++){
    __syncthreads();                                // xraw ready
    #pragma unroll
    for (int k = 0; k < 10; k++){
      if (k < 9 || tid < 192){
        u16 x1 = xraw[gsrc[k] & 0xFFFFu];
        u16 x2 = xraw[gsrc[k] >> 16];
        u32 pk = (u32)f2us(us2f(x1)*gA[k]) | ((u32)f2us(us2f(x2)*gB[k]) << 16);
        *(u32*)&zsh[gdst[k]] = pk;
      }
    }
    __syncthreads();                                // zsh ready, xraw free
    if (cc == c0){
      b0 = *(const bf16x8*)&lwt[dd*72 + kq*8];
      b1 = *(const bf16x8*)&lwt[dd*72 + 32 + kq*8];
    }
    // prefetch next chunk into regs
    float2 pf[10];
    bool has = (cc + 1 < c1);
    if (has){
      #pragma unroll
      for (int k = 0; k < 10; k++){
        int i = tid + k*512;
        if (i < 4800){
          int c = i / 75, j = i - c*75;
          pf[k] = xsrc[(n*64 + c)*3750 + (cc+1)*75 + j];
        }
      }
    }
    #pragma unroll
    for (int it = 0; it < 5; it++){
      int T = wvi + it*8;
      int r0 = (T >> 2) * 16;
      bf16x8 a0 = *(const bf16x8*)&zsh[(r0 + m16)*72 + kq*8];
      bf16x8 a1 = *(const bf16x8*)&zsh[(r0 + m16)*72 + 32 + kq*8];
      f32x4 a = {0.f,0.f,0.f,0.f};
      a = __builtin_amdgcn_mfma_f32_16x16x32_bf16(a0, b0, a, 0, 0, 0);
      a = __builtin_amdgcn_mfma_f32_16x16x32_bf16(a1, b1, a, 0, 0, 0);
      // rows >=150 are zero-padded -> contribute 0; no guard needed here.
      #pragma unroll
      for (int q = 0; q < 4; q++){
        float y = a[q];
        s_acc[it*4 + q] += y;
        q_acc[it*4 + q] += y*y;
      }
    }
    if (has){
      #pragma unroll
      for (int k = 0; k < 10; k++){
        int i = tid + k*512;
        if (i < 4800){
          int c = i / 75, j = i - c*75;
          *(u32*)&xraw[c*154 + 2*j] = (u32)f2us(pf[k].x) | ((u32)f2us(pf[k].y) << 16);
        }
      }
    }
  }
  // one-time flush of register accumulators into LDS
  #pragma unroll
  for (int it = 0; it < 5; it++){
    int T = wvi + it*8;
    int r0 = (T >> 2) * 16;
    #pragma unroll
    for (int q = 0; q < 4; q++){
      int r = r0 + kq*4 + q;
      if (r < 150){
        int v = r - 25*((r*41) >> 10);              // r % 25, valid r<160
        atomicAdd(&colacc[v*66 + dd], s_acc[it*4 + q]);
        atomicAdd(&colacc[1650 + v*66 + dd], q_acc[it*4 + q]);
      }
    }
  }
  __syncthreads();
  // non-atomic private partial slice (coalesced)
  float* dst = ws + WS_PARTIAL + blockIdx.x*3200;
  for (int i = tid; i < 3200; i += 512){
    int f = (i < 1600) ? i : (i - 1600);
    int v = f >> 6, d = f & 63;
    dst[i] = colacc[((i < 1600) ? 0 : 1650) + v*66 + d];
  }
}

// K5a: reduce 512 partial slices -> WS_COLSTAT (no atomics anywhere).
__global__ __launch_bounds__(256) void k5a(float* __restrict__ ws)
{
  __shared__ float red[256];
  int tid = threadIdx.x;
  int f = blockIdx.x*64 + (tid & 63);
  int bsub = tid >> 6;                              // 0..3
  const float* src = ws + WS_PARTIAL + f;
  float acc = 0.f;
  #pragma unroll 8
  for (int b = bsub; b < 512; b += 4)
    acc += src[b*3200];
  red[tid] = acc;
  __syncthreads();
  if (tid < 64){
    float t = red[tid] + red[tid+64] + red[tid+128] + red[tid+192];
    ws[WS_COLSTAT + f] = t;
  }
}

// K5b: fold col stats + gbn/bbn (shifted index) into per-(v,d) affine a,b
__global__ __launch_bounds__(256) void k5b(const float* __restrict__ gbn, const float* __restrict__ bbn,
                                           float* __restrict__ ws)
{
  int i = blockIdx.x*256 + threadIdx.x;
  if (i >= 1600) return;
  int v = i >> 6, d = i & 63;
  float s = ws[WS_COLSTAT + i], q = ws[WS_COLSTAT + 1600 + i];
  float m = s / 19200.f;
  float var = q / 19200.f - m*m;
  float rs = rsqrtf(var + EPSF);
  int vi = (v + d) % 25;
  int f = vi*64 + d;
  float a = gbn[f] * rs;
  ws[WS_ABN + i] = a;
  ws[WS_BBN + i] = bbn[f] - m*a;
}

// K6: GEMM apply pass + BN + shift_out + residual + relu; coalesced store.
// Gather + epilogue index math hoisted into registers (chunk-invariant).
__global__ __launch_bounds__(512, 4) void k6(const float* __restrict__ x0,
    const float* __restrict__ Lw, float* __restrict__ out, float* __restrict__ ws)
{
  __shared__ u16 xraw[64*154];
  __shared__ u16 zsh[160*72];
  __shared__ u16 lwt[64*72];
  __shared__ float gate[1600];
  __shared__ float affA[1650];
  __shared__ float affB[1650];
  int tid = threadIdx.x;
  int n = blockIdx.x >> 3, e8 = blockIdx.x & 7;
  int c0 = (e8*50) >> 3, c1 = ((e8+1)*50) >> 3;
  const float2* xsrc = (const float2*)x0;

  for (int i = tid; i < 1600; i += 512){
    gate[i] = ws[WS_GATE + i];
    int v = i >> 6, d = i & 63;
    affA[v*66 + d] = ws[WS_ABN + i];
    affB[v*66 + d] = ws[WS_BBN + i];
  }
  for (int i = tid; i < 4096; i += 512){
    int c = i >> 6, d = i & 63;
    lwt[d*72 + c] = f2us(Lw[c*64 + d]);
  }
  for (int i = tid; i < 640; i += 512){ int c = i & 63, r = 150 + (i >> 6); zsh[r*72 + c] = 0; }
  for (int i = tid; i < 4800; i += 512){
    int c = i / 75, j = i - c*75;
    float2 xy = xsrc[(n*64 + c)*3750 + c0*75 + j];
    *(u32*)&xraw[c*154 + 2*j] = (u32)f2us(xy.x) | ((u32)f2us(xy.y) << 16);
  }
  __syncthreads();                                  // gate ready for precompute

  // --- chunk-invariant gather slots (pairs of adjacent c) ---
  u32 gsrc[10]; int gdst[10]; float gA[10], gB[10];
  #pragma unroll
  for (int k = 0; k < 10; k++){
    int p = tid + k*512;
    if (k < 9 || p < 4800){
      int cp = (p & 31)*2, r = p >> 5;
      int v = r % 25;
      int base = r - v;
      int u1 = (v + cp) % 25;
      int u2 = (v + cp + 1) % 25;
      gsrc[k] = (u32)(cp*154 + base + u1) | ((u32)((cp+1)*154 + base + u2) << 16);
      gdst[k] = r*72 + cp;
      gA[k] = gate[v*64 + cp];
      gB[k] = gate[v*64 + cp + 1];
    }
  }

  int lane = tid & 63, wvi = tid >> 6;
  int m16 = lane & 15, kq = lane >> 4;
  int dd = (wvi & 3)*16 + m16;

  // --- chunk-invariant epilogue slots: packed {xraw idx | affine offset} ---
  u32 eidx[20];
  #pragma unroll
  for (int it = 0; it < 5; it++){
    int T = wvi + it*8;
    int r0 = (T >> 2) * 16;
    #pragma unroll
    for (int q = 0; q < 4; q++){
      int r = r0 + kq*4 + q;
      u32 e = 0xFFFFu;
      if (r < 150){
        int v = r % 25;
        int u = (v + dd) % 25;
        e = (u32)(dd*154 + (r - v) + u) | ((u32)(v*66 + dd) << 16);
      }
      eidx[it*4 + q] = e;
    }
  }

  bf16x8 b0, b1;

  for (int cc = c0; cc < c1; cc++){
    __syncthreads();                                // xraw ready
    #pragma unroll
    for (int k = 0; k < 10; k++){
      if (k < 9 || tid < 192){
        u16 x1 = xraw[gsrc[k] & 0xFFFFu];
        u16 x2 = xraw[gsrc[k] >> 16];
        u32 pk = (u32)f2us(us2f(x1)*gA[k]) | ((u32)f2us(us2f(x2)*gB[k]) << 16);
        *(u32*)&zsh[gdst[k]] = pk;
      }
    }
    __syncthreads();                                // zsh ready (xraw still = residual)
    if (cc == c0){
      b0 = *(const bf16x8*)&lwt[dd*72 + kq*8];
      b1 = *(const bf16x8*)&lwt[dd*72 + 32 + kq*8];
    }
    float2 pf[10];
    bool has = (cc + 1 < c1);
    if (has){
      #pragma unroll
      for (int k = 0; k < 10; k++){
        int i = tid + k*512;
        if (i < 4800){
          int c = i / 75, j = i - c*75;
          pf[k] = xsrc[(n*64 + c)*3750 + (cc+1)*75 + j];
        }
      }
    }
    f32x4 acc[5];
    #pragma unroll
    for (int it = 0; it < 5; it++){
      int T = wvi + it*8;
      int r0 = (T >> 2) * 16;
      bf16x8 a0 = *(const bf16x8*)&zsh[(r0 + m16)*72 + kq*8];
      bf16x8 a1 = *(const bf16x8*)&zsh[(r0 + m16)*72 + 32 + kq*8];
      f32x4 a = {0.f,0.f,0.f,0.f};
      a = __builtin_amdgcn_mfma_f32_16x16x32_bf16(a0, b0, a, 0, 0, 0);
      a = __builtin_amdgcn_mfma_f32_16x16x32_bf16(a1, b1, a, 0, 0, 0);
      acc[it] = a;
    }
    // epilogue: rotate + BN + residual + relu, in place (unique reader=writer per slot)
    #pragma unroll
    for (int s = 0; s < 20; s++){
      u32 e = eidx[s];
      if ((e & 0xFFFFu) != 0xFFFFu){
        int idx = (int)(e & 0xFFFFu), ao = (int)(e >> 16);
        float resid = us2f(xraw[idx]);
        float val = acc[s>>2][s&3] * affA[ao] + affB[ao] + resid;
        xraw[idx] = f2us(fmaxf(val, 0.f));
      }
    }
    __syncthreads();                                // epilogue done
    for (int i = tid; i < 4800; i += 512){
      int d = i / 75, j = i - d*75;
      u32 pk = *(const u32*)&xraw[d*154 + 2*j];
      float2 o; o.x = us2f((u16)(pk & 0xFFFFu)); o.y = us2f((u16)(pk >> 16));
      ((float2*)out)[(n*64 + d)*3750 + cc*75 + j] = o;
    }
    __syncthreads();                                // store done, xraw free
    if (has){
      #pragma unroll
      for (int k = 0; k < 10; k++){
        int i = tid + k*512;
        if (i < 4800){
          int c = i / 75, j = i - c*75;
          *(u32*)&xraw[c*154 + 2*j] = (u32)f2us(pf[k].x) | ((u32)f2us(pf[k].y) << 16);
        }
      }
    }
  }
}

extern "C" void kernel_launch(void* const* d_in, const int* in_sizes, int n_in,
                              void* d_out, int out_size, void* d_ws, size_t ws_size,
                              hipStream_t stream)
{
  const float* x0  = (const float*)d_in[0];
  // d_in[1] shift_in, d_in[2] shift_out: closed-form rotations used instead
  const float* Wv  = (const float*)d_in[3];
  const float* bv  = (const float*)d_in[4];
  const float* gv  = (const float*)d_in[5];
  const float* bev = (const float*)d_in[6];
  const float* Wt  = (const float*)d_in[7];
  const float* bt  = (const float*)d_in[8];
  const float* gt  = (const float*)d_in[9];
  const float* bet = (const float*)d_in[10];
  const float* Ws_ = (const float*)d_in[11];
  // d_in[12] bs: cancels exactly in BN — dropped
  const float* gs  = (const float*)d_in[13];
  const float* bes = (const float*)d_in[14];
  const float* Wv2 = (const float*)d_in[15];
  const float* bv2 = (const float*)d_in[16];
  const float* Wt2 = (const float*)d_in[17];
  const float* bt2 = (const float*)d_in[18];
  const float* Lw  = (const float*)d_in[19];
  // d_in[20] Lb: cancels exactly in final BN — dropped
  const float* gbn = (const float*)d_in[21];
  const float* bbn = (const float*)d_in[22];
  float* out = (float*)d_out;
  float* ws = (float*)d_ws;

  k_zero<<<dim3(14), dim3(256), 0, stream>>>(ws + WS_PART1, 3584);
  k1<<<dim3(4096), dim3(256), 0, stream>>>(x0, Wv, bv, Wt, bt, ws);
  k2<<<dim3(256), dim3(256), 0, stream>>>(Ws_, gv, bev, gt, bet, ws);
  k3<<<dim3(82), dim3(256), 0, stream>>>(gs, bes, ws);
  k4<<<dim3(82), dim3(256), 0, stream>>>(Wt2, bt2, Wv2, bv2, out + 30720000, ws);
  k5<<<dim3(512), dim3(512), 0, stream>>>(x0, Lw, ws);
  k5a<<<dim3(50), dim3(256), 0, stream>>>(ws);
  k5b<<<dim3(7), dim3(256), 0, stream>>>(gbn, bbn, ws);
  k6<<<dim3(512), dim3(512), 0, stream>>>(x0, Lw, out, ws);
}

// Round 3
// 492.826 us; speedup vs baseline: 1.2309x; 1.2309x over previous
//
#include <hip/hip_runtime.h>

typedef unsigned short u16;
typedef unsigned int   u32;

#define EPSF 1e-5f

typedef __attribute__((ext_vector_type(8))) short bf16x8;
typedef __attribute__((ext_vector_type(4))) float f32x4;

__device__ __forceinline__ u16 f2us(float f){
  union { float f; u32 i; } v; v.f = f;
  u32 i = v.i;
  return (u16)((i + 0x7FFFu + ((i >> 16) & 1u)) >> 16);   // RNE f32->bf16
}
__device__ __forceinline__ float us2f(u16 u){
  union { u32 i; float f; } v; v.i = ((u32)u) << 16; return v.f;
}
__device__ __forceinline__ float hswish(float x){
  return x * fminf(fmaxf(x + 3.f, 0.f), 6.f) * (1.f/6.f);
}
__device__ __forceinline__ float sigm(float x){ return 1.f / (1.f + expf(-x)); }

// ---- workspace layout (fp32 elements) ----
#define WS_PARTIAL 0          // 512*3200 = 1638400 (reuses XV/XT/XS space, dead after k3)
#define WS_XV      0          // 1228800
#define WS_XT      1228800    // 102400
#define WS_XS      1331200    // 1331200
#define WS_S       2662400    // 20800
#define WS_GATE    2683200    // 1600
#define WS_PART1   2684800    // 256
#define WS_ACCXS   2685056    // 128
#define WS_COLSTAT 2685184    // 3200
#define WS_ABN     2688384    // 1600
#define WS_BBN     2689984    // 1600

__global__ __launch_bounds__(256) void k_zero(float* p, int cnt){
  int i = blockIdx.x*256 + threadIdx.x;
  if (i < cnt) p[i] = 0.f;
}

// K1: per (n,c) slab: xv_pre[n,c,t], xt_pre[n,c,v], global BN stat partials.
__global__ __launch_bounds__(256) void k1(const float* __restrict__ x0,
    const float* __restrict__ Wv, const float* __restrict__ bv,
    const float* __restrict__ Wt, const float* __restrict__ bt,
    float* __restrict__ ws)
{
  __shared__ float slab[7500];
  __shared__ float wvc[25];
  __shared__ float wts[300];
  __shared__ float colS[25];
  __shared__ float red[8];
  int blk = blockIdx.x;           // n*64 + c
  int c = blk & 63;
  int tid = threadIdx.x;
  const float4* src = (const float4*)(x0) + blk*1875;
  float4* dst = (float4*)slab;
  for (int i = tid; i < 1875; i += 256) dst[i] = src[i];
  int cm = c % 25;
  if (tid < 25){ wvc[tid] = Wv[(tid - cm + 25) % 25]; colS[tid] = 0.f; }
  for (int i = tid; i < 300; i += 256) wts[i] = Wt[i];
  __syncthreads();
  float bvf = bv[0];
  float s1 = 0.f, s2 = 0.f;
  float ca[25];
  #pragma unroll
  for (int u = 0; u < 25; u++) ca[u] = 0.f;
  for (int t = tid; t < 300; t += 256){
    const float* row = &slab[t*25];
    float wt = wts[t];
    float xv = bvf;
    #pragma unroll
    for (int u = 0; u < 25; u++){
      float xf = row[u];
      xv += wvc[u] * xf;
      ca[u] += wt * xf;
    }
    ws[WS_XV + blk*300 + t] = xv;
    s1 += xv; s2 += xv*xv;
  }
  #pragma unroll
  for (int off = 32; off >= 1; off >>= 1){
    s1 += __shfl_xor(s1, off);
    s2 += __shfl_xor(s2, off);
    #pragma unroll
    for (int u = 0; u < 25; u++) ca[u] += __shfl_xor(ca[u], off);
  }
  int lane = tid & 63, wvi = tid >> 6;
  if (lane == 0){
    #pragma unroll
    for (int u = 0; u < 25; u++) atomicAdd(&colS[u], ca[u]);
    red[wvi] = s1; red[4 + wvi] = s2;
  }
  __syncthreads();
  if (wvi == 0){
    float btf = bt[0];
    float val = 0.f;
    if (lane < 25){
      val = colS[(lane + cm) % 25] + btf;
      ws[WS_XT + blk*25 + lane] = val;
    }
    float t1 = val, t2 = val*val;
    #pragma unroll
    for (int off = 32; off >= 1; off >>= 1){ t1 += __shfl_xor(t1, off); t2 += __shfl_xor(t2, off); }
    if (lane == 0){
      float* slot = &ws[WS_PART1 + (blk & 63)*4];
      atomicAdd(slot+0, red[0]+red[1]+red[2]+red[3]);
      atomicAdd(slot+1, red[4]+red[5]+red[6]+red[7]);
      atomicAdd(slot+2, t1);
      atomicAdd(slot+3, t2);
    }
  }
}

// K2: xs_pre[n,o,l] = sum_c Ws[o,c]*xs[n,c,l]; per-o stats.
__global__ __launch_bounds__(256) void k2(
    const float* __restrict__ Ws_, const float* __restrict__ gv, const float* __restrict__ bev,
    const float* __restrict__ gt, const float* __restrict__ bet,
    float* __restrict__ ws)
{
  __shared__ float xsc[64*82];
  __shared__ float wsl[64*65];
  __shared__ float accs[128];
  __shared__ float bnp[4];
  int tid = threadIdx.x;
  int n = blockIdx.x >> 2;
  int chunk = blockIdx.x & 3;
  int l0 = chunk * 82;
  int cw = (325 - l0 < 82) ? (325 - l0) : 82;
  if (tid < 64){
    float p0 = ws[WS_PART1 + tid*4 + 0];
    float p1 = ws[WS_PART1 + tid*4 + 1];
    float p2 = ws[WS_PART1 + tid*4 + 2];
    float p3 = ws[WS_PART1 + tid*4 + 3];
    #pragma unroll
    for (int off = 32; off >= 1; off >>= 1){
      p0 += __shfl_xor(p0, off); p1 += __shfl_xor(p1, off);
      p2 += __shfl_xor(p2, off); p3 += __shfl_xor(p3, off);
    }
    if (tid == 0){
      float Mv = 1228800.f;
      float mv = p0 / Mv;
      float varv = p1 / Mv - mv*mv;
      float av = gv[0] * rsqrtf(varv + EPSF);
      bnp[0] = av; bnp[1] = bev[0] - mv*av;
      float Mt = 102400.f;
      float mt = p2 / Mt;
      float vart = p3 / Mt - mt*mt;
      float at = gt[0] * rsqrtf(vart + EPSF);
      bnp[2] = at; bnp[3] = bet[0] - mt*at;
    }
  }
  for (int i = tid; i < 4096; i += 256){
    int o = i >> 6, cc = i & 63;
    wsl[o*65 + cc] = Ws_[i];
  }
  if (tid < 128) accs[tid] = 0.f;
  __syncthreads();
  float a_v = bnp[0], b_v = bnp[1], a_t = bnp[2], b_t = bnp[3];
  for (int i = tid; i < 64*cw; i += 256){
    int ch = i / cw, li = i - ch*cw;
    int f = ch*325 + l0 + li;
    float e;
    if (f < 1600) e = ws[WS_XT + n*1600 + f] * a_t + b_t;
    else          e = ws[WS_XV + n*19200 + (f - 1600)] * a_v + b_v;
    xsc[ch*82 + li] = hswish(e);
  }
  __syncthreads();
  int o = tid & 63;
  float s1 = 0.f, s2 = 0.f;
  for (int i = tid; i < 64*cw; i += 256){
    int li = i >> 6;
    float acc = 0.f;
    #pragma unroll 8
    for (int cc = 0; cc < 64; cc++)
      acc += wsl[o*65 + cc] * xsc[cc*82 + li];
    ws[WS_XS + (n*64 + o)*325 + l0 + li] = acc;
    s1 += acc; s2 += acc*acc;
  }
  atomicAdd(&accs[o*2+0], s1);
  atomicAdd(&accs[o*2+1], s2);
  __syncthreads();
  if (tid < 128) atomicAdd(&ws[WS_ACCXS + tid], accs[tid]);
}

// K3: S[d,l] = sum_n hardswish(bn_s(xs_pre[n,d,l]))
__global__ __launch_bounds__(256) void k3(const float* __restrict__ gs, const float* __restrict__ bes,
                                          float* __restrict__ ws)
{
  int i = blockIdx.x*256 + threadIdx.x;
  if (i >= 20800) return;
  int dch = i / 325, l = i - dch*325;
  float s1 = ws[WS_ACCXS + dch*2], s2 = ws[WS_ACCXS + dch*2 + 1];
  float m = s1 / 20800.f;
  float var = s2 / 20800.f - m*m;
  float a = gs[dch] * rsqrtf(var + EPSF);
  float b = bes[dch] - m*a;
  float sum = 0.f;
  for (int n = 0; n < 64; n++)
    sum += hswish(ws[WS_XS + (n*64 + dch)*325 + l] * a + b);
  ws[WS_S + i] = sum;
}

// K4: x_time out + gate
__global__ __launch_bounds__(256) void k4(const float* __restrict__ Wt2, const float* __restrict__ bt2,
    const float* __restrict__ Wv2, const float* __restrict__ bv2,
    float* __restrict__ out2, float* __restrict__ ws)
{
  int i = blockIdx.x*256 + threadIdx.x;
  if (i < 19200){
    int o = i / 300, t = i - o*300;
    float acc = 0.f;
    #pragma unroll 8
    for (int dd = 0; dd < 64; dd++)
      acc += Wt2[o*64+dd] * ws[WS_S + dd*325 + t];
    out2[i] = sigm(acc * (1.f/64.f) + bt2[o]);
  } else if (i < 20800){
    int g = i - 19200;
    int v = g >> 6, cc = g & 63;
    float acc = 0.f;
    #pragma unroll 8
    for (int dd = 0; dd < 64; dd++)
      acc += Wv2[cc*64+dd] * ws[WS_S + dd*325 + 300 + v];
    ws[WS_GATE + v*64 + cc] = tanhf(sigm(acc * (1.f/64.f) + bv2[cc])) + 1.f;
  }
}

// K5: GEMM stats pass. launch_bounds(512,2) -> 128-VGPR budget (2 blocks/CU, matches
// LDS cap). Slim chunk-invariant hoist: packed gather src (u32) + gate LDS offset;
// gather dst recomputed (cheap). Register sum/sumsq accumulators, LDS flush once,
// non-atomic private partial slice.
__global__ __launch_bounds__(512, 2) void k5(const float* __restrict__ x0,
    const float* __restrict__ Lw, float* __restrict__ ws)
{
  __shared__ u16 xraw[64*154];
  __shared__ u16 zsh[160*72];
  __shared__ u16 lwt[64*72];
  __shared__ float gate[1600];
  __shared__ float colacc[3300];
  int tid = threadIdx.x;
  int n = blockIdx.x >> 3, e8 = blockIdx.x & 7;
  int c0 = (e8*50) >> 3, c1 = ((e8+1)*50) >> 3;   // 6 or 7 chunks of 6 t-steps
  const float2* xsrc = (const float2*)x0;

  for (int i = tid; i < 1600; i += 512) gate[i] = ws[WS_GATE + i];
  for (int i = tid; i < 4096; i += 512){
    int c = i >> 6, d = i & 63;                    // coalesced Lw read
    lwt[d*72 + c] = f2us(Lw[c*64 + d]);
  }
  for (int i = tid; i < 3300; i += 512) colacc[i] = 0.f;
  for (int i = tid; i < 640; i += 512){ int c = i & 63, r = 150 + (i >> 6); zsh[r*72 + c] = 0; }
  // stage first chunk
  for (int i = tid; i < 4800; i += 512){
    int c = i / 75, j = i - c*75;
    float2 xy = xsrc[(n*64 + c)*3750 + c0*75 + j];
    *(u32*)&xraw[c*154 + 2*j] = (u32)f2us(xy.x) | ((u32)f2us(xy.y) << 16);
  }

  // --- chunk-invariant gather slots (pairs of adjacent c): packed src + gate offset ---
  u32 gsrc[10]; int gadr[10];
  #pragma unroll
  for (int k = 0; k < 10; k++){
    int p = tid + k*512;
    if (k < 9 || p < 4800){
      int cp = (p & 31)*2, r = p >> 5;
      int v = r - 25*((r*41) >> 10);                // r % 25, r < 160
      int base = r - v;
      int w = v + cp;
      int u1 = w - 25*((w*41) >> 10);               // (v+cp) % 25, w < 88
      int w2 = w + 1;
      int u2 = w2 - 25*((w2*41) >> 10);
      gsrc[k] = (u32)(cp*154 + base + u1) | ((u32)((cp+1)*154 + base + u2) << 16);
      gadr[k] = v*64 + cp;
    }
  }

  int lane = tid & 63, wvi = tid >> 6;
  int m16 = lane & 15, kq = lane >> 4;
  int dd = (wvi & 3)*16 + m16;
  bf16x8 b0, b1;
  float s_acc[20], q_acc[20];
  #pragma unroll
  for (int z = 0; z < 20; z++){ s_acc[z] = 0.f; q_acc[z] = 0.f; }

  for (int cc = c0; cc < c1; cc++){
    __syncthreads();                                // xraw ready
    #pragma unroll
    for (int k = 0; k < 10; k++){
      if (k < 9 || tid < 192){
        int p = tid + k*512;
        int dst = (p >> 5)*72 + (p & 31)*2;
        float gA = gate[gadr[k]];
        float gB = gate[gadr[k] + 1];
        u16 x1 = xraw[gsrc[k] & 0xFFFFu];
        u16 x2 = xraw[gsrc[k] >> 16];
        u32 pk = (u32)f2us(us2f(x1)*gA) | ((u32)f2us(us2f(x2)*gB) << 16);
        *(u32*)&zsh[dst] = pk;
      }
    }
    __syncthreads();                                // zsh ready, xraw free
    if (cc == c0){
      b0 = *(const bf16x8*)&lwt[dd*72 + kq*8];
      b1 = *(const bf16x8*)&lwt[dd*72 + 32 + kq*8];
    }
    // prefetch next chunk into regs
    float2 pf[10];
    bool has = (cc + 1 < c1);
    if (has){
      #pragma unroll
      for (int k = 0; k < 10; k++){
        int i = tid + k*512;
        if (i < 4800){
          int c = i / 75, j = i - c*75;
          pf[k] = xsrc[(n*64 + c)*3750 + (cc+1)*75 + j];
        }
      }
    }
    #pragma unroll
    for (int it = 0; it < 5; it++){
      int T = wvi + it*8;
      int r0 = (T >> 2) * 16;
      bf16x8 a0 = *(const bf16x8*)&zsh[(r0 + m16)*72 + kq*8];
      bf16x8 a1 = *(const bf16x8*)&zsh[(r0 + m16)*72 + 32 + kq*8];
      f32x4 a = {0.f,0.f,0.f,0.f};
      a = __builtin_amdgcn_mfma_f32_16x16x32_bf16(a0, b0, a, 0, 0, 0);
      a = __builtin_amdgcn_mfma_f32_16x16x32_bf16(a1, b1, a, 0, 0, 0);
      // rows >=150 are zero-padded -> contribute 0; no guard needed here.
      #pragma unroll
      for (int q = 0; q < 4; q++){
        float y = a[q];
        s_acc[it*4 + q] += y;
        q_acc[it*4 + q] += y*y;
      }
    }
    if (has){
      #pragma unroll
      for (int k = 0; k < 10; k++){
        int i = tid + k*512;
        if (i < 4800){
          int c = i / 75, j = i - c*75;
          *(u32*)&xraw[c*154 + 2*j] = (u32)f2us(pf[k].x) | ((u32)f2us(pf[k].y) << 16);
        }
      }
    }
  }
  // one-time flush of register accumulators into LDS
  #pragma unroll
  for (int it = 0; it < 5; it++){
    int T = wvi + it*8;
    int r0 = (T >> 2) * 16;
    #pragma unroll
    for (int q = 0; q < 4; q++){
      int r = r0 + kq*4 + q;
      if (r < 150){
        int v = r - 25*((r*41) >> 10);              // r % 25, valid r<160
        atomicAdd(&colacc[v*66 + dd], s_acc[it*4 + q]);
        atomicAdd(&colacc[1650 + v*66 + dd], q_acc[it*4 + q]);
      }
    }
  }
  __syncthreads();
  // non-atomic private partial slice (coalesced)
  float* dst = ws + WS_PARTIAL + blockIdx.x*3200;
  for (int i = tid; i < 3200; i += 512){
    int f = (i < 1600) ? i : (i - 1600);
    int v = f >> 6, d = f & 63;
    dst[i] = colacc[((i < 1600) ? 0 : 1650) + v*66 + d];
  }
}

// K5a: reduce 512 partial slices -> WS_COLSTAT (no atomics anywhere).
__global__ __launch_bounds__(256) void k5a(float* __restrict__ ws)
{
  __shared__ float red[256];
  int tid = threadIdx.x;
  int f = blockIdx.x*64 + (tid & 63);
  int bsub = tid >> 6;                              // 0..3
  const float* src = ws + WS_PARTIAL + f;
  float acc = 0.f;
  #pragma unroll 8
  for (int b = bsub; b < 512; b += 4)
    acc += src[b*3200];
  red[tid] = acc;
  __syncthreads();
  if (tid < 64){
    float t = red[tid] + red[tid+64] + red[tid+128] + red[tid+192];
    ws[WS_COLSTAT + f] = t;
  }
}

// K5b: fold col stats + gbn/bbn (shifted index) into per-(v,d) affine a,b
__global__ __launch_bounds__(256) void k5b(const float* __restrict__ gbn, const float* __restrict__ bbn,
                                           float* __restrict__ ws)
{
  int i = blockIdx.x*256 + threadIdx.x;
  if (i >= 1600) return;
  int v = i >> 6, d = i & 63;
  float s = ws[WS_COLSTAT + i], q = ws[WS_COLSTAT + 1600 + i];
  float m = s / 19200.f;
  float var = q / 19200.f - m*m;
  float rs = rsqrtf(var + EPSF);
  int vi = (v + d) % 25;
  int f = vi*64 + d;
  float a = gbn[f] * rs;
  ws[WS_ABN + i] = a;
  ws[WS_BBN + i] = bbn[f] - m*a;
}

// K6: GEMM apply pass + BN + shift_out + residual + relu; coalesced store.
// launch_bounds(512,2) -> 128-VGPR budget; slim hoist (gather src+gate offset,
// epilogue packed idx); dst recomputed.
__global__ __launch_bounds__(512, 2) void k6(const float* __restrict__ x0,
    const float* __restrict__ Lw, float* __restrict__ out, float* __restrict__ ws)
{
  __shared__ u16 xraw[64*154];
  __shared__ u16 zsh[160*72];
  __shared__ u16 lwt[64*72];
  __shared__ float gate[1600];
  __shared__ float affA[1650];
  __shared__ float affB[1650];
  int tid = threadIdx.x;
  int n = blockIdx.x >> 3, e8 = blockIdx.x & 7;
  int c0 = (e8*50) >> 3, c1 = ((e8+1)*50) >> 3;
  const float2* xsrc = (const float2*)x0;

  for (int i = tid; i < 1600; i += 512){
    gate[i] = ws[WS_GATE + i];
    int v = i >> 6, d = i & 63;
    affA[v*66 + d] = ws[WS_ABN + i];
    affB[v*66 + d] = ws[WS_BBN + i];
  }
  for (int i = tid; i < 4096; i += 512){
    int c = i >> 6, d = i & 63;
    lwt[d*72 + c] = f2us(Lw[c*64 + d]);
  }
  for (int i = tid; i < 640; i += 512){ int c = i & 63, r = 150 + (i >> 6); zsh[r*72 + c] = 0; }
  for (int i = tid; i < 4800; i += 512){
    int c = i / 75, j = i - c*75;
    float2 xy = xsrc[(n*64 + c)*3750 + c0*75 + j];
    *(u32*)&xraw[c*154 + 2*j] = (u32)f2us(xy.x) | ((u32)f2us(xy.y) << 16);
  }

  // --- chunk-invariant gather slots: packed src + gate offset ---
  u32 gsrc[10]; int gadr[10];
  #pragma unroll
  for (int k = 0; k < 10; k++){
    int p = tid + k*512;
    if (k < 9 || p < 4800){
      int cp = (p & 31)*2, r = p >> 5;
      int v = r - 25*((r*41) >> 10);
      int base = r - v;
      int w = v + cp;
      int u1 = w - 25*((w*41) >> 10);
      int w2 = w + 1;
      int u2 = w2 - 25*((w2*41) >> 10);
      gsrc[k] = (u32)(cp*154 + base + u1) | ((u32)((cp+1)*154 + base + u2) << 16);
      gadr[k] = v*64 + cp;
    }
  }

  int lane = tid & 63, wvi = tid >> 6;
  int m16 = lane & 15, kq = lane >> 4;
  int dd = (wvi & 3)*16 + m16;

  // --- chunk-invariant epilogue slots: packed {xraw idx | affine offset} ---
  u32 eidx[20];
  #pragma unroll
  for (int it = 0; it < 5; it++){
    int T = wvi + it*8;
    int r0 = (T >> 2) * 16;
    #pragma unroll
    for (int q = 0; q < 4; q++){
      int r = r0 + kq*4 + q;
      u32 e = 0xFFFFu;
      if (r < 150){
        int v = r - 25*((r*41) >> 10);
        int w = v + dd;
        int u = w - 25*((w*41) >> 10);
        e = (u32)(dd*154 + (r - v) + u) | ((u32)(v*66 + dd) << 16);
      }
      eidx[it*4 + q] = e;
    }
  }

  bf16x8 b0, b1;

  for (int cc = c0; cc < c1; cc++){
    __syncthreads();                                // xraw ready
    #pragma unroll
    for (int k = 0; k < 10; k++){
      if (k < 9 || tid < 192){
        int p = tid + k*512;
        int dst = (p >> 5)*72 + (p & 31)*2;
        float gA = gate[gadr[k]];
        float gB = gate[gadr[k] + 1];
        u16 x1 = xraw[gsrc[k] & 0xFFFFu];
        u16 x2 = xraw[gsrc[k] >> 16];
        u32 pk = (u32)f2us(us2f(x1)*gA) | ((u32)f2us(us2f(x2)*gB) << 16);
        *(u32*)&zsh[dst] = pk;
      }
    }
    __syncthreads();                                // zsh ready (xraw still = residual)
    if (cc == c0){
      b0 = *(const bf16x8*)&lwt[dd*72 + kq*8];
      b1 = *(const bf16x8*)&lwt[dd*72 + 32 + kq*8];
    }
    float2 pf[10];
    bool has = (cc + 1 < c1);
    if (has){
      #pragma unroll
      for (int k = 0; k < 10; k++){
        int i = tid + k*512;
        if (i < 4800){
          int c = i / 75, j = i - c*75;
          pf[k] = xsrc[(n*64 + c)*3750 + (cc+1)*75 + j];
        }
      }
    }
    f32x4 acc[5];
    #pragma unroll
    for (int it = 0; it < 5; it++){
      int T = wvi + it*8;
      int r0 = (T >> 2) * 16;
      bf16x8 a0 = *(const bf16x8*)&zsh[(r0 + m16)*72 + kq*8];
      bf16x8 a1 = *(const bf16x8*)&zsh[(r0 + m16)*72 + 32 + kq*8];
      f32x4 a = {0.f,0.f,0.f,0.f};
      a = __builtin_amdgcn_mfma_f32_16x16x32_bf16(a0, b0, a, 0, 0, 0);
      a = __builtin_amdgcn_mfma_f32_16x16x32_bf16(a1, b1, a, 0, 0, 0);
      acc[it] = a;
    }
    // epilogue: rotate + BN + residual + relu, in place (unique reader=writer per slot)
    #pragma unroll
    for (int s = 0; s < 20; s++){
      u32 e = eidx[s];
      if ((e & 0xFFFFu) != 0xFFFFu){
        int idx = (int)(e & 0xFFFFu), ao = (int)(e >> 16);
        float resid = us2f(xraw[idx]);
        float val = acc[s>>2][s&3] * affA[ao] + affB[ao] + resid;
        xraw[idx] = f2us(fmaxf(val, 0.f));
      }
    }
    __syncthreads();                                // epilogue done
    for (int i = tid; i < 4800; i += 512){
      int d = i / 75, j = i - d*75;
      u32 pk = *(const u32*)&xraw[d*154 + 2*j];
      float2 o; o.x = us2f((u16)(pk & 0xFFFFu)); o.y = us2f((u16)(pk >> 16));
      ((float2*)out)[(n*64 + d)*3750 + cc*75 + j] = o;
    }
    __syncthreads();                                // store done, xraw free
    if (has){
      #pragma unroll
      for (int k = 0; k < 10; k++){
        int i = tid + k*512;
        if (i < 4800){
          int c = i / 75, j = i - c*75;
          *(u32*)&xraw[c*154 + 2*j] = (u32)f2us(pf[k].x) | ((u32)f2us(pf[k].y) << 16);
        }
      }
    }
  }
}

extern "C" void kernel_launch(void* const* d_in, const int* in_sizes, int n_in,
                              void* d_out, int out_size, void* d_ws, size_t ws_size,
                              hipStream_t stream)
{
  const float* x0  = (const float*)d_in[0];
  // d_in[1] shift_in, d_in[2] shift_out: closed-form rotations used instead
  const float* Wv  = (const float*)d_in[3];
  const float* bv  = (const float*)d_in[4];
  const float* gv  = (const float*)d_in[5];
  const float* bev = (const float*)d_in[6];
  const float* Wt  = (const float*)d_in[7];
  const float* bt  = (const float*)d_in[8];
  const float* gt  = (const float*)d_in[9];
  const float* bet = (const float*)d_in[10];
  const float* Ws_ = (const float*)d_in[11];
  // d_in[12] bs: cancels exactly in BN — dropped
  const float* gs  = (const float*)d_in[13];
  const float* bes = (const float*)d_in[14];
  const float* Wv2 = (const float*)d_in[15];
  const float* bv2 = (const float*)d_in[16];
  const float* Wt2 = (const float*)d_in[17];
  const float* bt2 = (const float*)d_in[18];
  const float* Lw  = (const float*)d_in[19];
  // d_in[20] Lb: cancels exactly in final BN — dropped
  const float* gbn = (const float*)d_in[21];
  const float* bbn = (const float*)d_in[22];
  float* out = (float*)d_out;
  float* ws = (float*)d_ws;

  k_zero<<<dim3(14), dim3(256), 0, stream>>>(ws + WS_PART1, 3584);
  k1<<<dim3(4096), dim3(256), 0, stream>>>(x0, Wv, bv, Wt, bt, ws);
  k2<<<dim3(256), dim3(256), 0, stream>>>(Ws_, gv, bev, gt, bet, ws);
  k3<<<dim3(82), dim3(256), 0, stream>>>(gs, bes, ws);
  k4<<<dim3(82), dim3(256), 0, stream>>>(Wt2, bt2, Wv2, bv2, out + 30720000, ws);
  k5<<<dim3(512), dim3(512), 0, stream>>>(x0, Lw, ws);
  k5a<<<dim3(50), dim3(256), 0, stream>>>(ws);
  k5b<<<dim3(7), dim3(256), 0, stream>>>(gbn, bbn, ws);
  k6<<<dim3(512), dim3(512), 0, stream>>>(x0, Lw, out, ws);
}

// Round 5
// 488.554 us; speedup vs baseline: 1.2417x; 1.0087x over previous
//
#include <hip/hip_runtime.h>

typedef unsigned short u16;
typedef unsigned int   u32;

#define EPSF 1e-5f

typedef __attribute__((ext_vector_type(8))) short bf16x8;
typedef __attribute__((ext_vector_type(4))) float f32x4;

__device__ __forceinline__ u16 f2us(float f){
  union { float f; u32 i; } v; v.f = f;
  u32 i = v.i;
  return (u16)((i + 0x7FFFu + ((i >> 16) & 1u)) >> 16);   // RNE f32->bf16
}
__device__ __forceinline__ float us2f(u16 u){
  union { u32 i; float f; } v; v.i = ((u32)u) << 16; return v.f;
}
__device__ __forceinline__ float hswish(float x){
  return x * fminf(fmaxf(x + 3.f, 0.f), 6.f) * (1.f/6.f);
}
__device__ __forceinline__ float sigm(float x){ return 1.f / (1.f + expf(-x)); }

// ---- workspace layout (fp32 elements) ----
#define WS_PARTIAL 0          // 512*3200 = 1638400 (reuses XV/XT/XS space, dead after k3)
#define WS_XV      0          // 1228800
#define WS_XT      1228800    // 102400
#define WS_XS      1331200    // 1331200
#define WS_S       2662400    // 20800
#define WS_GATE    2683200    // 1600
#define WS_PART1   2684800    // 256
#define WS_ACCXS   2685056    // 128
#define WS_COLSTAT 2685184    // 3200
#define WS_ABN     2688384    // 1600
#define WS_BBN     2689984    // 1600
#define WS_YWS     2692096    // 15360000 u32 slots (bf16 y, rotated layout; 3750 u32/row) — optional

__global__ __launch_bounds__(256) void k_zero(float* p, int cnt){
  int i = blockIdx.x*256 + threadIdx.x;
  if (i < cnt) p[i] = 0.f;
}

// K1: per (n,c) slab: xv_pre[n,c,t], xt_pre[n,c,v], global BN stat partials.
__global__ __launch_bounds__(256) void k1(const float* __restrict__ x0,
    const float* __restrict__ Wv, const float* __restrict__ bv,
    const float* __restrict__ Wt, const float* __restrict__ bt,
    float* __restrict__ ws)
{
  __shared__ float slab[7500];
  __shared__ float wvc[25];
  __shared__ float wts[300];
  __shared__ float colS[25];
  __shared__ float red[8];
  int blk = blockIdx.x;           // n*64 + c
  int c = blk & 63;
  int tid = threadIdx.x;
  const float4* src = (const float4*)(x0) + blk*1875;
  float4* dst = (float4*)slab;
  for (int i = tid; i < 1875; i += 256) dst[i] = src[i];
  int cm = c % 25;
  if (tid < 25){ wvc[tid] = Wv[(tid - cm + 25) % 25]; colS[tid] = 0.f; }
  for (int i = tid; i < 300; i += 256) wts[i] = Wt[i];
  __syncthreads();
  float bvf = bv[0];
  float s1 = 0.f, s2 = 0.f;
  float ca[25];
  #pragma unroll
  for (int u = 0; u < 25; u++) ca[u] = 0.f;
  for (int t = tid; t < 300; t += 256){
    const float* row = &slab[t*25];
    float wt = wts[t];
    float xv = bvf;
    #pragma unroll
    for (int u = 0; u < 25; u++){
      float xf = row[u];
      xv += wvc[u] * xf;
      ca[u] += wt * xf;
    }
    ws[WS_XV + blk*300 + t] = xv;
    s1 += xv; s2 += xv*xv;
  }
  #pragma unroll
  for (int off = 32; off >= 1; off >>= 1){
    s1 += __shfl_xor(s1, off);
    s2 += __shfl_xor(s2, off);
    #pragma unroll
    for (int u = 0; u < 25; u++) ca[u] += __shfl_xor(ca[u], off);
  }
  int lane = tid & 63, wvi = tid >> 6;
  if (lane == 0){
    #pragma unroll
    for (int u = 0; u < 25; u++) atomicAdd(&colS[u], ca[u]);
    red[wvi] = s1; red[4 + wvi] = s2;
  }
  __syncthreads();
  if (wvi == 0){
    float btf = bt[0];
    float val = 0.f;
    if (lane < 25){
      val = colS[(lane + cm) % 25] + btf;
      ws[WS_XT + blk*25 + lane] = val;
    }
    float t1 = val, t2 = val*val;
    #pragma unroll
    for (int off = 32; off >= 1; off >>= 1){ t1 += __shfl_xor(t1, off); t2 += __shfl_xor(t2, off); }
    if (lane == 0){
      float* slot = &ws[WS_PART1 + (blk & 63)*4];
      atomicAdd(slot+0, red[0]+red[1]+red[2]+red[3]);
      atomicAdd(slot+1, red[4]+red[5]+red[6]+red[7]);
      atomicAdd(slot+2, t1);
      atomicAdd(slot+3, t2);
    }
  }
}

// K2: xs_pre[n,o,l] = sum_c Ws[o,c]*xs[n,c,l]; per-o stats.
__global__ __launch_bounds__(256) void k2(
    const float* __restrict__ Ws_, const float* __restrict__ gv, const float* __restrict__ bev,
    const float* __restrict__ gt, const float* __restrict__ bet,
    float* __restrict__ ws)
{
  __shared__ float xsc[64*82];
  __shared__ float wsl[64*65];
  __shared__ float accs[128];
  __shared__ float bnp[4];
  int tid = threadIdx.x;
  int n = blockIdx.x >> 2;
  int chunk = blockIdx.x & 3;
  int l0 = chunk * 82;
  int cw = (325 - l0 < 82) ? (325 - l0) : 82;
  if (tid < 64){
    float p0 = ws[WS_PART1 + tid*4 + 0];
    float p1 = ws[WS_PART1 + tid*4 + 1];
    float p2 = ws[WS_PART1 + tid*4 + 2];
    float p3 = ws[WS_PART1 + tid*4 + 3];
    #pragma unroll
    for (int off = 32; off >= 1; off >>= 1){
      p0 += __shfl_xor(p0, off); p1 += __shfl_xor(p1, off);
      p2 += __shfl_xor(p2, off); p3 += __shfl_xor(p3, off);
    }
    if (tid == 0){
      float Mv = 1228800.f;
      float mv = p0 / Mv;
      float varv = p1 / Mv - mv*mv;
      float av = gv[0] * rsqrtf(varv + EPSF);
      bnp[0] = av; bnp[1] = bev[0] - mv*av;
      float Mt = 102400.f;
      float mt = p2 / Mt;
      float vart = p3 / Mt - mt*mt;
      float at = gt[0] * rsqrtf(vart + EPSF);
      bnp[2] = at; bnp[3] = bet[0] - mt*at;
    }
  }
  for (int i = tid; i < 4096; i += 256){
    int o = i >> 6, cc = i & 63;
    wsl[o*65 + cc] = Ws_[i];
  }
  if (tid < 128) accs[tid] = 0.f;
  __syncthreads();
  float a_v = bnp[0], b_v = bnp[1], a_t = bnp[2], b_t = bnp[3];
  for (int i = tid; i < 64*cw; i += 256){
    int ch = i / cw, li = i - ch*cw;
    int f = ch*325 + l0 + li;
    float e;
    if (f < 1600) e = ws[WS_XT + n*1600 + f] * a_t + b_t;
    else          e = ws[WS_XV + n*19200 + (f - 1600)] * a_v + b_v;
    xsc[ch*82 + li] = hswish(e);
  }
  __syncthreads();
  int o = tid & 63;
  float s1 = 0.f, s2 = 0.f;
  for (int i = tid; i < 64*cw; i += 256){
    int li = i >> 6;
    float acc = 0.f;
    #pragma unroll 8
    for (int cc = 0; cc < 64; cc++)
      acc += wsl[o*65 + cc] * xsc[cc*82 + li];
    ws[WS_XS + (n*64 + o)*325 + l0 + li] = acc;
    s1 += acc; s2 += acc*acc;
  }
  atomicAdd(&accs[o*2+0], s1);
  atomicAdd(&accs[o*2+1], s2);
  __syncthreads();
  if (tid < 128) atomicAdd(&ws[WS_ACCXS + tid], accs[tid]);
}

// K3: S[d,l] += sum over 8 n's of hardswish(bn_s(xs_pre[n,d,l])); grid (82, 8).
__global__ __launch_bounds__(256) void k3(const float* __restrict__ gs, const float* __restrict__ bes,
                                          float* __restrict__ ws)
{
  int i = blockIdx.x*256 + threadIdx.x;
  if (i >= 20800) return;
  int dch = i / 325, l = i - dch*325;
  float s1 = ws[WS_ACCXS + dch*2], s2 = ws[WS_ACCXS + dch*2 + 1];
  float m = s1 / 20800.f;
  float var = s2 / 20800.f - m*m;
  float a = gs[dch] * rsqrtf(var + EPSF);
  float b = bes[dch] - m*a;
  float sum = 0.f;
  int n0 = blockIdx.y * 8;
  for (int n = n0; n < n0 + 8; n++)
    sum += hswish(ws[WS_XS + (n*64 + dch)*325 + l] * a + b);
  atomicAdd(&ws[WS_S + i], sum);
}

// K4: x_time out + gate
__global__ __launch_bounds__(256) void k4(const float* __restrict__ Wt2, const float* __restrict__ bt2,
    const float* __restrict__ Wv2, const float* __restrict__ bv2,
    float* __restrict__ out2, float* __restrict__ ws)
{
  int i = blockIdx.x*256 + threadIdx.x;
  if (i < 19200){
    int o = i / 300, t = i - o*300;
    float acc = 0.f;
    #pragma unroll 8
    for (int dd = 0; dd < 64; dd++)
      acc += Wt2[o*64+dd] * ws[WS_S + dd*325 + t];
    out2[i] = sigm(acc * (1.f/64.f) + bt2[o]);
  } else if (i < 20800){
    int g = i - 19200;
    int v = g >> 6, cc = g & 63;
    float acc = 0.f;
    #pragma unroll 8
    for (int dd = 0; dd < 64; dd++)
      acc += Wv2[cc*64+dd] * ws[WS_S + dd*325 + 300 + v];
    ws[WS_GATE + v*64 + cc] = tanhf(sigm(acc * (1.f/64.f) + bv2[cc])) + 1.f;
  }
}

// K5y: single GEMM pass: stats (reg accumulators -> colacc -> private partials)
// AND (if storeY) writes rotated bf16 y to WS_YWS (3750 u32/row) via in-LDS scatter.
__global__ __launch_bounds__(512, 2) void k5y(const float* __restrict__ x0,
    const float* __restrict__ Lw, float* __restrict__ ws, const int storeY)
{
  __shared__ u16 xraw[64*154];
  __shared__ u16 zsh[160*72];
  __shared__ u16 lwt[64*72];
  __shared__ float gate[1600];
  __shared__ float colacc[3300];
  int tid = threadIdx.x;
  int n = blockIdx.x >> 3, e8 = blockIdx.x & 7;
  int c0 = (e8*50) >> 3, c1 = ((e8+1)*50) >> 3;   // 6 or 7 chunks of 6 t-steps
  const float2* xsrc = (const float2*)x0;
  u32* yws = (u32*)(ws + WS_YWS);

  for (int i = tid; i < 1600; i += 512) gate[i] = ws[WS_GATE + i];
  for (int i = tid; i < 4096; i += 512){
    int c = i >> 6, d = i & 63;                    // coalesced Lw read
    lwt[d*72 + c] = f2us(Lw[c*64 + d]);
  }
  for (int i = tid; i < 3300; i += 512) colacc[i] = 0.f;
  for (int i = tid; i < 640; i += 512){ int c = i & 63, r = 150 + (i >> 6); zsh[r*72 + c] = 0; }
  // stage first chunk
  for (int i = tid; i < 4800; i += 512){
    int c = i / 75, j = i - c*75;
    float2 xy = xsrc[(n*64 + c)*3750 + c0*75 + j];
    *(u32*)&xraw[c*154 + 2*j] = (u32)f2us(xy.x) | ((u32)f2us(xy.y) << 16);
  }

  // --- chunk-invariant gather slots (pairs of adjacent c): packed src + gate offset ---
  u32 gsrc[10]; int gadr[10];
  #pragma unroll
  for (int k = 0; k < 10; k++){
    int p = tid + k*512;
    if (k < 9 || p < 4800){
      int cp = (p & 31)*2, r = p >> 5;
      int v = r - 25*((r*41) >> 10);                // r % 25, r < 160
      int base = r - v;
      int w = v + cp;
      int u1 = w - 25*((w*41) >> 10);               // (v+cp) % 25, w < 88
      int w2 = w + 1;
      int u2 = w2 - 25*((w2*41) >> 10);
      gsrc[k] = (u32)(cp*154 + base + u1) | ((u32)((cp+1)*154 + base + u2) << 16);
      gadr[k] = v*64 + cp;
    }
  }

  int lane = tid & 63, wvi = tid >> 6;
  int m16 = lane & 15, kq = lane >> 4;
  int dd = (wvi & 3)*16 + m16;

  // --- chunk-invariant scatter slots: xraw idx (0xFFFF sentinel for pad rows) ---
  u32 eidx[20];
  #pragma unroll
  for (int it = 0; it < 5; it++){
    int T = wvi + it*8;
    int r0 = (T >> 2) * 16;
    #pragma unroll
    for (int q = 0; q < 4; q++){
      int r = r0 + kq*4 + q;
      u32 e = 0xFFFFu;
      if (r < 150){
        int v = r - 25*((r*41) >> 10);
        int w = v + dd;
        int u = w - 25*((w*41) >> 10);
        e = (u32)(dd*154 + (r - v) + u);
      }
      eidx[it*4 + q] = e;
    }
  }

  bf16x8 b0, b1;
  float s_acc[20], q_acc[20];
  #pragma unroll
  for (int z = 0; z < 20; z++){ s_acc[z] = 0.f; q_acc[z] = 0.f; }

  for (int cc = c0; cc < c1; cc++){
    __syncthreads();                                // xraw ready
    #pragma unroll
    for (int k = 0; k < 10; k++){
      if (k < 9 || tid < 192){
        int p = tid + k*512;
        int dst = (p >> 5)*72 + (p & 31)*2;
        float gA = gate[gadr[k]];
        float gB = gate[gadr[k] + 1];
        u16 x1 = xraw[gsrc[k] & 0xFFFFu];
        u16 x2 = xraw[gsrc[k] >> 16];
        u32 pk = (u32)f2us(us2f(x1)*gA) | ((u32)f2us(us2f(x2)*gB) << 16);
        *(u32*)&zsh[dst] = pk;
      }
    }
    __syncthreads();                                // zsh ready, xraw gather-reads done
    if (cc == c0){
      b0 = *(const bf16x8*)&lwt[dd*72 + kq*8];
      b1 = *(const bf16x8*)&lwt[dd*72 + 32 + kq*8];
    }
    // prefetch next chunk into regs
    float2 pf[10];
    bool has = (cc + 1 < c1);
    if (has){
      #pragma unroll
      for (int k = 0; k < 10; k++){
        int i = tid + k*512;
        if (i < 4800){
          int c = i / 75, j = i - c*75;
          pf[k] = xsrc[(n*64 + c)*3750 + (cc+1)*75 + j];
        }
      }
    }
    f32x4 acc[5];
    #pragma unroll
    for (int it = 0; it < 5; it++){
      int T = wvi + it*8;
      int r0 = (T >> 2) * 16;
      bf16x8 a0 = *(const bf16x8*)&zsh[(r0 + m16)*72 + kq*8];
      bf16x8 a1 = *(const bf16x8*)&zsh[(r0 + m16)*72 + 32 + kq*8];
      f32x4 a = {0.f,0.f,0.f,0.f};
      a = __builtin_amdgcn_mfma_f32_16x16x32_bf16(a0, b0, a, 0, 0, 0);
      a = __builtin_amdgcn_mfma_f32_16x16x32_bf16(a1, b1, a, 0, 0, 0);
      acc[it] = a;
      // stats: pad rows contribute exactly 0
      #pragma unroll
      for (int q = 0; q < 4; q++){
        float y = a[q];
        s_acc[it*4 + q] += y;
        q_acc[it*4 + q] += y*y;
      }
    }
    if (storeY){
      // scatter rotated y into xraw (input no longer needed this chunk)
      #pragma unroll
      for (int s = 0; s < 20; s++){
        u32 e = eidx[s];
        if (e != 0xFFFFu) xraw[e] = f2us(acc[s>>2][s&3]);
      }
      __syncthreads();                              // scatter done
      for (int i = tid; i < 4800; i += 512){
        int d = i / 75, j = i - d*75;
        yws[(n*64 + d)*3750 + cc*75 + j] = *(const u32*)&xraw[d*154 + 2*j];
      }
    }
    __syncthreads();                                // xraw free for prefetch write
    if (has){
      #pragma unroll
      for (int k = 0; k < 10; k++){
        int i = tid + k*512;
        if (i < 4800){
          int c = i / 75, j = i - c*75;
          *(u32*)&xraw[c*154 + 2*j] = (u32)f2us(pf[k].x) | ((u32)f2us(pf[k].y) << 16);
        }
      }
    }
  }
  // one-time flush of register accumulators into LDS
  #pragma unroll
  for (int it = 0; it < 5; it++){
    int T = wvi + it*8;
    int r0 = (T >> 2) * 16;
    #pragma unroll
    for (int q = 0; q < 4; q++){
      int r = r0 + kq*4 + q;
      if (r < 150){
        int v = r - 25*((r*41) >> 10);              // r % 25, valid r<160
        atomicAdd(&colacc[v*66 + dd], s_acc[it*4 + q]);
        atomicAdd(&colacc[1650 + v*66 + dd], q_acc[it*4 + q]);
      }
    }
  }
  __syncthreads();
  // non-atomic private partial slice (coalesced)
  float* dst = ws + WS_PARTIAL + blockIdx.x*3200;
  for (int i = tid; i < 3200; i += 512){
    int f = (i < 1600) ? i : (i - 1600);
    int v = f >> 6, d = f & 63;
    dst[i] = colacc[((i < 1600) ? 0 : 1650) + v*66 + d];
  }
}

// K5a: reduce 512 partial slices -> WS_COLSTAT (no atomics anywhere).
__global__ __launch_bounds__(256) void k5a(float* __restrict__ ws)
{
  __shared__ float red[256];
  int tid = threadIdx.x;
  int f = blockIdx.x*64 + (tid & 63);
  int bsub = tid >> 6;                              // 0..3
  const float* src = ws + WS_PARTIAL + f;
  float acc = 0.f;
  #pragma unroll 8
  for (int b = bsub; b < 512; b += 4)
    acc += src[b*3200];
  red[tid] = acc;
  __syncthreads();
  if (tid < 64){
    float t = red[tid] + red[tid+64] + red[tid+128] + red[tid+192];
    ws[WS_COLSTAT + f] = t;
  }
}

// K5b: fold col stats + gbn/bbn into per-column affine a,b.
// rot=1: store indexed by rotated column (u*64+d) for streaming k6n.
// rot=0: store indexed by pre-rotation (v*64+d) for fallback k6.
__global__ __launch_bounds__(256) void k5b(const float* __restrict__ gbn, const float* __restrict__ bbn,
                                           float* __restrict__ ws, const int rot)
{
  int i = blockIdx.x*256 + threadIdx.x;
  if (i >= 1600) return;
  int v = i >> 6, d = i & 63;
  float s = ws[WS_COLSTAT + i], q = ws[WS_COLSTAT + 1600 + i];
  float m = s / 19200.f;
  float var = q / 19200.f - m*m;
  float rs = rsqrtf(var + EPSF);
  int vi = (v + d) % 25;
  int f = vi*64 + d;
  float a = gbn[f] * rs;
  int o = rot ? (vi*64 + d) : i;
  ws[WS_ABN + o] = a;
  ws[WS_BBN + o] = bbn[f] - m*a;
}

// K6n: streaming finale: out = relu(bf16(y)*A[u,d] + B[u,d] + x0). 4096 blocks = (n,d) rows.
__global__ __launch_bounds__(256) void k6n(const float* __restrict__ x0,
    float* __restrict__ out, const float* __restrict__ ws)
{
  __shared__ float sA[25];
  __shared__ float sB[25];
  int row = blockIdx.x;                             // n*64 + d
  int d = row & 63;
  int tid = threadIdx.x;
  if (tid < 25)       sA[tid]      = ws[WS_ABN + tid*64 + d];
  else if (tid < 50)  sB[tid - 25] = ws[WS_BBN + (tid - 25)*64 + d];
  __syncthreads();
  const u32*    yrow = (const u32*)(ws + WS_YWS) + row*3750;
  const float2* xrow = (const float2*)x0 + row*3750;
  float2*       orow = (float2*)out + row*3750;
  for (int j = tid; j < 3750; j += 256){
    u32 pk = yrow[j];
    float2 xv = xrow[j];
    int u0 = (2*j) % 25;
    int u1 = (u0 == 24) ? 0 : (u0 + 1);
    float2 o;
    o.x = fmaxf(us2f((u16)(pk & 0xFFFFu)) * sA[u0] + sB[u0] + xv.x, 0.f);
    o.y = fmaxf(us2f((u16)(pk >> 16))     * sA[u1] + sB[u1] + xv.y, 0.f);
    orow[j] = o;
  }
}

// K6 (fallback, only if workspace too small for y-store): GEMM apply pass.
__global__ __launch_bounds__(512, 2) void k6(const float* __restrict__ x0,
    const float* __restrict__ Lw, float* __restrict__ out, float* __restrict__ ws)
{
  __shared__ u16 xraw[64*154];
  __shared__ u16 zsh[160*72];
  __shared__ u16 lwt[64*72];
  __shared__ float gate[1600];
  __shared__ float affA[1650];
  __shared__ float affB[1650];
  int tid = threadIdx.x;
  int n = blockIdx.x >> 3, e8 = blockIdx.x & 7;
  int c0 = (e8*50) >> 3, c1 = ((e8+1)*50) >> 3;
  const float2* xsrc = (const float2*)x0;

  for (int i = tid; i < 1600; i += 512){
    gate[i] = ws[WS_GATE + i];
    int v = i >> 6, d = i & 63;
    affA[v*66 + d] = ws[WS_ABN + i];
    affB[v*66 + d] = ws[WS_BBN + i];
  }
  for (int i = tid; i < 4096; i += 512){
    int c = i >> 6, d = i & 63;
    lwt[d*72 + c] = f2us(Lw[c*64 + d]);
  }
  for (int i = tid; i < 640; i += 512){ int c = i & 63, r = 150 + (i >> 6); zsh[r*72 + c] = 0; }
  for (int i = tid; i < 4800; i += 512){
    int c = i / 75, j = i - c*75;
    float2 xy = xsrc[(n*64 + c)*3750 + c0*75 + j];
    *(u32*)&xraw[c*154 + 2*j] = (u32)f2us(xy.x) | ((u32)f2us(xy.y) << 16);
  }

  u32 gsrc[10]; int gadr[10];
  #pragma unroll
  for (int k = 0; k < 10; k++){
    int p = tid + k*512;
    if (k < 9 || p < 4800){
      int cp = (p & 31)*2, r = p >> 5;
      int v = r - 25*((r*41) >> 10);
      int base = r - v;
      int w = v + cp;
      int u1 = w - 25*((w*41) >> 10);
      int w2 = w + 1;
      int u2 = w2 - 25*((w2*41) >> 10);
      gsrc[k] = (u32)(cp*154 + base + u1) | ((u32)((cp+1)*154 + base + u2) << 16);
      gadr[k] = v*64 + cp;
    }
  }

  int lane = tid & 63, wvi = tid >> 6;
  int m16 = lane & 15, kq = lane >> 4;
  int dd = (wvi & 3)*16 + m16;

  u32 eidx[20];
  #pragma unroll
  for (int it = 0; it < 5; it++){
    int T = wvi + it*8;
    int r0 = (T >> 2) * 16;
    #pragma unroll
    for (int q = 0; q < 4; q++){
      int r = r0 + kq*4 + q;
      u32 e = 0xFFFFu;
      if (r < 150){
        int v = r - 25*((r*41) >> 10);
        int w = v + dd;
        int u = w - 25*((w*41) >> 10);
        e = (u32)(dd*154 + (r - v) + u) | ((u32)(v*66 + dd) << 16);
      }
      eidx[it*4 + q] = e;
    }
  }

  bf16x8 b0, b1;

  for (int cc = c0; cc < c1; cc++){
    __syncthreads();
    #pragma unroll
    for (int k = 0; k < 10; k++){
      if (k < 9 || tid < 192){
        int p = tid + k*512;
        int dst = (p >> 5)*72 + (p & 31)*2;
        float gA = gate[gadr[k]];
        float gB = gate[gadr[k] + 1];
        u16 x1 = xraw[gsrc[k] & 0xFFFFu];
        u16 x2 = xraw[gsrc[k] >> 16];
        u32 pk = (u32)f2us(us2f(x1)*gA) | ((u32)f2us(us2f(x2)*gB) << 16);
        *(u32*)&zsh[dst] = pk;
      }
    }
    __syncthreads();
    if (cc == c0){
      b0 = *(const bf16x8*)&lwt[dd*72 + kq*8];
      b1 = *(const bf16x8*)&lwt[dd*72 + 32 + kq*8];
    }
    float2 pf[10];
    bool has = (cc + 1 < c1);
    if (has){
      #pragma unroll
      for (int k = 0; k < 10; k++){
        int i = tid + k*512;
        if (i < 4800){
          int c = i / 75, j = i - c*75;
          pf[k] = xsrc[(n*64 + c)*3750 + (cc+1)*75 + j];
        }
      }
    }
    f32x4 acc[5];
    #pragma unroll
    for (int it = 0; it < 5; it++){
      int T = wvi + it*8;
      int r0 = (T >> 2) * 16;
      bf16x8 a0 = *(const bf16x8*)&zsh[(r0 + m16)*72 + kq*8];
      bf16x8 a1 = *(const bf16x8*)&zsh[(r0 + m16)*72 + 32 + kq*8];
      f32x4 a = {0.f,0.f,0.f,0.f};
      a = __builtin_amdgcn_mfma_f32_16x16x32_bf16(a0, b0, a, 0, 0, 0);
      a = __builtin_amdgcn_mfma_f32_16x16x32_bf16(a1, b1, a, 0, 0, 0);
      acc[it] = a;
    }
    #pragma unroll
    for (int s = 0; s < 20; s++){
      u32 e = eidx[s];
      if ((e & 0xFFFFu) != 0xFFFFu){
        int idx = (int)(e & 0xFFFFu), ao = (int)(e >> 16);
        float resid = us2f(xraw[idx]);
        float val = acc[s>>2][s&3] * affA[ao] + affB[ao] + resid;
        xraw[idx] = f2us(fmaxf(val, 0.f));
      }
    }
    __syncthreads();
    for (int i = tid; i < 4800; i += 512){
      int d = i / 75, j = i - d*75;
      u32 pk = *(const u32*)&xraw[d*154 + 2*j];
      float2 o; o.x = us2f((u16)(pk & 0xFFFFu)); o.y = us2f((u16)(pk >> 16));
      ((float2*)out)[(n*64 + d)*3750 + cc*75 + j] = o;
    }
    __syncthreads();
    if (has){
      #pragma unroll
      for (int k = 0; k < 10; k++){
        int i = tid + k*512;
        if (i < 4800){
          int c = i / 75, j = i - c*75;
          *(u32*)&xraw[c*154 + 2*j] = (u32)f2us(pf[k].x) | ((u32)f2us(pf[k].y) << 16);
        }
      }
    }
  }
}

extern "C" void kernel_launch(void* const* d_in, const int* in_sizes, int n_in,
                              void* d_out, int out_size, void* d_ws, size_t ws_size,
                              hipStream_t stream)
{
  const float* x0  = (const float*)d_in[0];
  // d_in[1] shift_in, d_in[2] shift_out: closed-form rotations used instead
  const float* Wv  = (const float*)d_in[3];
  const float* bv  = (const float*)d_in[4];
  const float* gv  = (const float*)d_in[5];
  const float* bev = (const float*)d_in[6];
  const float* Wt  = (const float*)d_in[7];
  const float* bt  = (const float*)d_in[8];
  const float* gt  = (const float*)d_in[9];
  const float* bet = (const float*)d_in[10];
  const float* Ws_ = (const float*)d_in[11];
  // d_in[12] bs: cancels exactly in BN — dropped
  const float* gs  = (const float*)d_in[13];
  const float* bes = (const float*)d_in[14];
  const float* Wv2 = (const float*)d_in[15];
  const float* bv2 = (const float*)d_in[16];
  const float* Wt2 = (const float*)d_in[17];
  const float* bt2 = (const float*)d_in[18];
  const float* Lw  = (const float*)d_in[19];
  // d_in[20] Lb: cancels exactly in final BN — dropped
  const float* gbn = (const float*)d_in[21];
  const float* bbn = (const float*)d_in[22];
  float* out = (float*)d_out;
  float* ws = (float*)d_ws;

  const int big = (ws_size >= (size_t)(WS_YWS + 15360000) * 4) ? 1 : 0;

  k_zero<<<dim3(14), dim3(256), 0, stream>>>(ws + WS_PART1, 3584);
  k_zero<<<dim3(82), dim3(256), 0, stream>>>(ws + WS_S, 20800);
  k1<<<dim3(4096), dim3(256), 0, stream>>>(x0, Wv, bv, Wt, bt, ws);
  k2<<<dim3(256), dim3(256), 0, stream>>>(Ws_, gv, bev, gt, bet, ws);
  k3<<<dim3(82, 8), dim3(256), 0, stream>>>(gs, bes, ws);
  k4<<<dim3(82), dim3(256), 0, stream>>>(Wt2, bt2, Wv2, bv2, out + 30720000, ws);
  k5y<<<dim3(512), dim3(512), 0, stream>>>(x0, Lw, ws, big);
  k5a<<<dim3(50), dim3(256), 0, stream>>>(ws);
  k5b<<<dim3(7), dim3(256), 0, stream>>>(gbn, bbn, ws, big);
  if (big){
    k6n<<<dim3(4096), dim3(256), 0, stream>>>(x0, out, ws);
  } else {
    k6<<<dim3(512), dim3(512), 0, stream>>>(x0, Lw, out, ws);
  }
}